// Round 1
// baseline (130.867 us; speedup 1.0000x reference)
//
#include <hip/hip_runtime.h>

static constexpr int OHW = 12, NSP = 144;

// 4-byte-aligned float4 for (possibly) unaligned x loads; gfx950 global
// unaligned dwordx4 is supported, so this still emits one load.
typedef float float4a __attribute__((ext_vector_type(4), aligned(4)));

__device__ __forceinline__ void fma4(float4& a, float s, const float4& w) {
    a.x = fmaf(s, w.x, a.x);
    a.y = fmaf(s, w.y, a.y);
    a.z = fmaf(s, w.z, a.z);
    a.w = fmaf(s, w.w, a.w);
}

__device__ __forceinline__ float4 shfl_xor4(const float4& v, int m) {
    float4 r;
    r.x = __shfl_xor(v.x, m);
    r.y = __shfl_xor(v.y, m);
    r.z = __shfl_xor(v.z, m);
    r.w = __shfl_xor(v.w, m);
    return r;
}

// Compute one (j) group directly from x. The block's 4 n's are 4 consecutive
// ow in the same (b, oh) row, so the 4 nn-values for a fixed (k,i) are 4
// consecutive floats in x: one dwordx4 per i. Same load count as the old
// T4 path; build_T is gone.
// xb = x + b*256*196 + oh*14 + ow0.
__device__ __forceinline__ void do_j(const float* __restrict__ xb,
                                     const float4* __restrict__ W4,
                                     float4* __restrict__ Pl,
                                     int o, int k, int cg,
                                     int g_local, int lane) {
    float4 w[8];
    const float4* wp = W4 + (size_t)(o * 288 + k) * 32 + cg;
    #pragma unroll
    for (int i = 0; i < 8; ++i) w[i] = wp[i * 4];

    const int ic = k & 31;
    const int kk = k >> 5;               // kh*3+kw in [0,9)
    const int kh = (kk * 11) >> 5;       // kk/3 for kk in [0,9)
    const int kw = kk - 3 * kh;
    const float* xp = xb + ic * (8 * 196) + kh * 14 + kw;

    float4a v[8];
    #pragma unroll
    for (int i = 0; i < 8; ++i) v[i] = *(const float4a*)(xp + i * 196);

    float4 acc[4];
    #pragma unroll
    for (int nn = 0; nn < 4; ++nn) acc[nn] = make_float4(0.f, 0.f, 0.f, 0.f);
    #pragma unroll
    for (int i = 0; i < 8; ++i) {
        fma4(acc[0], v[i].x, w[i]);
        fma4(acc[1], v[i].y, w[i]);
        fma4(acc[2], v[i].z, w[i]);
        fma4(acc[3], v[i].w, w[i]);
    }
    #pragma unroll
    for (int nn = 0; nn < 4; ++nn)
        Pl[nn * 576 + g_local * 64 + lane] = acc[nn];
}

// ---------------------------------------------------------------------------
// caps_fused: block = (o, 4 n's). Phase 1: priors GEMM straight from x,
// thread = (cg, kg), 4-n weight amortization in registers. Handoff: two
// 9-slab LDS chunks, layout [nn][g][kgp][cg]. Phase 2: wave = one n,
// lane = (cg, kgp), k = kgp + 16*jj; routing fully intra-wave.
// ---------------------------------------------------------------------------
__global__ __launch_bounds__(256, 4)
void caps_fused(const float* __restrict__ x, const float4* __restrict__ W4,
                float* __restrict__ out) {
    __shared__ float4 Pl[4 * 9 * 64];   // 36,864 B -> 4 blocks/CU
    const int tid = threadIdx.x;
    const int o = blockIdx.y;
    const int nbase = blockIdx.x * 4;
    const int cg = tid & 3;
    const int kg = tid >> 2;     // [0,64)
    const int wv = tid >> 6;
    const int lane = tid & 63;

    // spatial base for the block's 4 n's (same b, oh; ow = ow0..ow0+3)
    const int b = nbase / NSP;
    const int rm = nbase - b * NSP;
    const int oh = rm / OHW;
    const int ow0 = rm - oh * OHW;
    const float* xb = x + (size_t)b * (256 * 196) + oh * 14 + ow0;

    float4 P[18];

    // ---- phase 1, chunk 0: g = wv + 4j in [0,9) ----
    #pragma unroll
    for (int j = 0; j < 5; ++j) {
        const int k = kg + 64 * j;
        const int g = wv + 4 * j;
        if (k < 288 && g < 9)
            do_j(xb, W4, Pl, o, k, cg, g, lane);
    }
    __syncthreads();
    #pragma unroll
    for (int jj = 0; jj < 9; ++jj)
        P[jj] = Pl[wv * 576 + jj * 64 + lane];
    __syncthreads();
    // ---- phase 1, chunk 1: g in [9,18) ----
    #pragma unroll
    for (int j = 0; j < 5; ++j) {
        const int k = kg + 64 * j;
        const int g = wv + 4 * j;
        if (k < 288 && g >= 9)
            do_j(xb, W4, Pl, o, k, cg, g - 9, lane);
    }
    __syncthreads();
    #pragma unroll
    for (int jj = 9; jj < 18; ++jj)
        P[jj] = Pl[wv * 576 + (jj - 9) * 64 + lane];

    // ---- phase 2: dynamic routing, wave = n (= nbase + wv) ----
    float lj[18];
    #pragma unroll
    for (int jj = 0; jj < 18; ++jj) lj[jj] = 0.f;
    float4 vq = make_float4(0.f, 0.f, 0.f, 0.f);

    #pragma unroll
    for (int it = 0; it < 3; ++it) {
        float4 svU = make_float4(0.f, 0.f, 0.f, 0.f);
        float S;
        if (it == 0) {
            #pragma unroll
            for (int jj = 0; jj < 18; ++jj) {
                svU.x += P[jj].x; svU.y += P[jj].y;
                svU.z += P[jj].z; svU.w += P[jj].w;
            }
            #pragma unroll
            for (int m = 4; m < 64; m <<= 1) {
                const float4 t = shfl_xor4(svU, m);
                svU.x += t.x; svU.y += t.y; svU.z += t.z; svU.w += t.w;
            }
            S = 288.0f;
        } else {
            S = 0.f;
            #pragma unroll
            for (int jj = 0; jj < 18; ++jj) {
                const float e = __expf(lj[jj]);   // |lj| small; no max needed
                S += e;
                fma4(svU, e, P[jj]);
            }
            #pragma unroll
            for (int m = 4; m < 64; m <<= 1) {
                const float4 t = shfl_xor4(svU, m);
                svU.x += t.x; svU.y += t.y; svU.z += t.z; svU.w += t.w;
                S += __shfl_xor(S, m);
            }
        }
        const float invS = __frcp_rn(S);
        float4 s;
        s.x = svU.x * invS; s.y = svU.y * invS;
        s.z = svU.z * invS; s.w = svU.w * invS;
        float sq = s.x * s.x + s.y * s.y + s.z * s.z + s.w * s.w;
        sq += __shfl_xor(sq, 1);
        sq += __shfl_xor(sq, 2);
        const float scale = __fsqrt_rn(sq) / (1.0f + sq);
        vq.x = s.x * scale; vq.y = s.y * scale;
        vq.z = s.z * scale; vq.w = s.w * scale;

        if (it < 2) {
            #pragma unroll
            for (int jj = 0; jj < 18; ++jj) {
                float d = P[jj].x * vq.x + P[jj].y * vq.y +
                          P[jj].z * vq.z + P[jj].w * vq.w;
                d += __shfl_xor(d, 1);
                d += __shfl_xor(d, 2);
                lj[jj] += d;
            }
        }
    }

    // ---- store: lanes kgp==0 write their c-quad ----
    if ((lane >> 2) == 0) {
        float* op = out + (size_t)(b * 512 + o * 16 + cg * 4) * NSP + (rm + wv);
        op[0 * NSP] = vq.x;
        op[1 * NSP] = vq.y;
        op[2 * NSP] = vq.z;
        op[3 * NSP] = vq.w;
    }
}

extern "C" void kernel_launch(void* const* d_in, const int* in_sizes, int n_in,
                              void* d_out, int out_size, void* d_ws, size_t ws_size,
                              hipStream_t stream) {
    const float* x  = (const float*)d_in[0];   // (4, 256, 14, 14)
    const float* wt = (const float*)d_in[1];   // (32, 288, 8, 16)
    float* out = (float*)d_out;                // (4, 512, 12, 12)
    caps_fused<<<dim3(144, 32), 256, 0, stream>>>(x, (const float4*)wt, out);
}